// Round 7
// baseline (158.307 us; speedup 1.0000x reference)
//
#include <hip/hip_runtime.h>
#include <math.h>

// ---------------------------------------------------------------------------
// A3C_LSTM_GA forward, batch=1.  No cross-WG sync anywhere.
//   K1 a3c_pre  (6 blocks x 256): image MLP; gates_h = hx@lstm_wh.T+lbh;
//                                 head-bias init out[0..4]
//   K2 a3c_scan (1 block x 768, amdgpu_num_vgpr(168)): GRU scan, pure VALU.
//       Thread t=2p+j owns gate-rows {2p,2p+1} col-half j as 32 NAMED h8
//       fragments (128 VGPRs, no arrays -> clean SSA); per step 16 broadcast
//       ds_read_b128 of its h-half, 128 v_dot2, shfl_xor(1) combines halves.
//       gi precomputed to LDS f16. Attention+fuse+lin fused at the end.
//   K3 a3c_post (4 blocks x 256): LSTM gates -> h/c -> head atomicAdd partials
// ---------------------------------------------------------------------------

typedef __fp16 h2 __attribute__((ext_vector_type(2)));
typedef __fp16 h4 __attribute__((ext_vector_type(4)));
typedef __fp16 h8 __attribute__((ext_vector_type(8)));

// ws layout (float offsets)
#define WS_IMG    0      // 128
#define WS_GATESH 128    // 1024
#define WS_FUSED  1152   // 256

__device__ __forceinline__ float dot4(const float4 a, const float4 b){
  return a.x*b.x + a.y*b.y + a.z*b.z + a.w*b.w;
}
__device__ __forceinline__ float sigm(float x){ return 1.f/(1.f+expf(-x)); }

#define P0(v) __builtin_shufflevector(v,v,0,1)
#define P1(v) __builtin_shufflevector(v,v,2,3)
#define P2(v) __builtin_shufflevector(v,v,4,5)
#define P3(v) __builtin_shufflevector(v,v,6,7)
#define PK(a,b) __builtin_amdgcn_cvt_pkrtz(a,b)
#define FD(w,e,acc) __builtin_amdgcn_fdot2(w,e,acc,false)

__device__ __forceinline__ h8 pack8(const float4 a, const float4 b){
  const h2 p0=PK(a.x,a.y), p1=PK(a.z,a.w), p2=PK(b.x,b.y), p3=PK(b.z,b.w);
  const h4 q0=__builtin_shufflevector(p0,p1,0,1,2,3);
  const h4 q1=__builtin_shufflevector(p2,p3,0,1,2,3);
  return __builtin_shufflevector(q0,q1,0,1,2,3,4,5,6,7);
}

// ------------------------------------------------------------------- K1
__global__ __launch_bounds__(256) void a3c_pre(
    const float* __restrict__ x,
    const float* __restrict__ i1w, const float* __restrict__ i1b,
    const float* __restrict__ i2w, const float* __restrict__ i2b,
    const float* __restrict__ i3w, const float* __restrict__ i3b,
    const float* __restrict__ hx,  const float* __restrict__ lwh,
    const float* __restrict__ lbh,
    const int*   __restrict__ tx,  const float* __restrict__ temb,
    const float* __restrict__ cw,  const float* __restrict__ cb,
    const float* __restrict__ acw, const float* __restrict__ acb,
    float* __restrict__ ws, float* __restrict__ out)
{
  const int b = blockIdx.x;
  const int t = threadIdx.x;

  if (b == 0) {
    // image MLP 400 -> 128 -> 128 -> 128
    __shared__ __align__(16) float x_lds[400];
    __shared__ __align__(16) float h1[128];
    __shared__ __align__(16) float h2s[128];
    x_lds[t] = x[t];
    if (t < 144) x_lds[256+t] = x[256+t];
    __syncthreads();
    {
      const int o = t>>1, half = t&1;
      const float4* wr = (const float4*)(i1w + o*400 + half*200);
      const float4* xr = (const float4*)(x_lds + half*200);
      float acc = 0.f;
      #pragma unroll 5
      for (int k=0;k<50;++k) acc += dot4(wr[k], xr[k]);
      acc += __shfl_down(acc, 1, 2);
      if (half == 0) h1[o] = fmaxf(acc + i1b[o], 0.f);
    }
    __syncthreads();
    if (t < 128){
      const float4* wr = (const float4*)(i2w + t*128);
      const float4* h4p = (const float4*)h1;
      float acc = i2b[t];
      #pragma unroll 8
      for (int k=0;k<32;++k) acc += dot4(wr[k], h4p[k]);
      h2s[t] = fmaxf(acc, 0.f);
    }
    __syncthreads();
    if (t < 128){
      const float4* wr = (const float4*)(i3w + t*128);
      const float4* h4p = (const float4*)h2s;
      float acc = i3b[t];
      #pragma unroll 8
      for (int k=0;k<32;++k) acc += dot4(wr[k], h4p[k]);
      ws[WS_IMG + t] = fmaxf(acc, 0.f);
    }

  } else if (b == 5) {
    // out[0..4] = bias + time-embedding partial of the heads
    if (t < 64){
      float tv = 0.f;
      if (t < 32) tv = temb[tx[0]*32 + t];
      #pragma unroll
      for (int o=0;o<5;++o){
        const float* wrow = (o==0) ? cw : (acw + (o-1)*288);
        float pr = (t < 32) ? tv*wrow[256+t] : 0.f;
        #pragma unroll
        for (int off=16; off; off>>=1) pr += __shfl_down(pr, off, 32);
        if (t == 0) out[o] = pr + ((o==0) ? cb[0] : acb[o-1]);
      }
    }

  } else {
    // blocks 1..4: gates_h = hx @ lstm_wh.T + lstm_bh
    __shared__ __align__(16) float hx_lds[256];
    hx_lds[t] = hx[t];
    __syncthreads();
    const int R = (b-1)*256 + t;
    const float4* wr = (const float4*)(lwh + R*256);
    const float4* h4p = (const float4*)hx_lds;
    float acc = lbh[R];
    #pragma unroll 8
    for (int k=0;k<64;++k) acc += dot4(wr[k], h4p[k]);
    ws[WS_GATESH + R] = acc;
  }
}

// ------------------------------------------------------------------- K2
__global__ __launch_bounds__(768)
__attribute__((amdgpu_waves_per_eu(3, 3), amdgpu_num_vgpr(168)))
void a3c_scan(
    const int*   __restrict__ inst, const float* __restrict__ emb,
    const float* __restrict__ gwi,  const float* __restrict__ gwh,
    const float* __restrict__ gbi,  const float* __restrict__ gbh,
    const float* __restrict__ aw,   const float* __restrict__ ab,
    const float* __restrict__ lw,   const float* __restrict__ lb,
    float* __restrict__ ws)
{
  const int t = threadIdx.x;           // final owner of gate-row t
  const int p = t >> 1;                // row pair: rows {2p, 2p+1}
  const int j = t & 1;                 // column half [128j, 128j+128)
  __shared__ __fp16 gi16[64*768];                   // 96 KB
  __shared__ __align__(16) __fp16 e16[2048];        // 4 KB  (emb_seq f16)
  __shared__ __align__(16) float h32[256];
  __shared__ __align__(16) __fp16 h16[256];
  __shared__ float pre[768];
  __shared__ float hn[256];
  __shared__ __align__(16) float f0[128];

  // emb_seq -> f16 LDS
  for (int i=t; i<2048; i+=768)
    e16[i] = (__fp16)emb[inst[i>>5]*32 + (i&31)];
  const float bh_t = gbh[t];
  const float bi_t = gbi[t];
  __syncthreads();

  // ---- gi16[s][t] = gru_wi[row t] . e_s + gbi[t]  (named regs only)
  {
    const float4* wp = (const float4*)(gwi + t*32);
    const float4 qa=wp[0], qb=wp[1], qc=wp[2], qd=wp[3],
                 qe=wp[4], qf=wp[5], qg=wp[6], qh=wp[7];
    const h2 wi0=PK(qa.x,qa.y), wi1=PK(qa.z,qa.w), wi2=PK(qb.x,qb.y), wi3=PK(qb.z,qb.w);
    const h2 wi4=PK(qc.x,qc.y), wi5=PK(qc.z,qc.w), wi6=PK(qd.x,qd.y), wi7=PK(qd.z,qd.w);
    const h2 wi8=PK(qe.x,qe.y), wi9=PK(qe.z,qe.w), wiA=PK(qf.x,qf.y), wiB=PK(qf.z,qf.w);
    const h2 wiC=PK(qg.x,qg.y), wiD=PK(qg.z,qg.w), wiE=PK(qh.x,qh.y), wiF=PK(qh.z,qh.w);
    for (int s=0;s<64;++s){
      const h8* ech = (const h8*)(e16 + s*32);
      const h8 e0=ech[0], e1=ech[1], e2=ech[2], e3=ech[3];
      float g = bi_t;
      g=FD(wi0,P0(e0),g); g=FD(wi1,P1(e0),g); g=FD(wi2,P2(e0),g); g=FD(wi3,P3(e0),g);
      g=FD(wi4,P0(e1),g); g=FD(wi5,P1(e1),g); g=FD(wi6,P2(e1),g); g=FD(wi7,P3(e1),g);
      g=FD(wi8,P0(e2),g); g=FD(wi9,P1(e2),g); g=FD(wiA,P2(e2),g); g=FD(wiB,P3(e2),g);
      g=FD(wiC,P0(e3),g); g=FD(wiD,P1(e3),g); g=FD(wiE,P2(e3),g); g=FD(wiF,P3(e3),g);
      gi16[s*768 + t] = (__fp16)g;
    }
  }

  // ---- weights: rows {2p,2p+1}, col-half j -> 32 NAMED h8 (128 VGPRs)
  h8 wA0,wA1,wA2,wA3,wA4,wA5,wA6,wA7,wA8,wA9,wAa,wAb,wAc,wAd,wAe,wAf;
  h8 wB0,wB1,wB2,wB3,wB4,wB5,wB6,wB7,wB8,wB9,wBa,wBb,wBc,wBd,wBe,wBf;
  {
    const float4* wp0 = (const float4*)(gwh + (2*p  )*256 + 128*j);
    const float4* wp1 = (const float4*)(gwh + (2*p+1)*256 + 128*j);
    #define LW(dst, base, c) dst = pack8((base)[2*(c)], (base)[2*(c)+1]);
    LW(wA0,wp0,0)  LW(wA1,wp0,1)  LW(wA2,wp0,2)  LW(wA3,wp0,3)
    LW(wA4,wp0,4)  LW(wA5,wp0,5)  LW(wA6,wp0,6)  LW(wA7,wp0,7)
    LW(wA8,wp0,8)  LW(wA9,wp0,9)  LW(wAa,wp0,10) LW(wAb,wp0,11)
    LW(wAc,wp0,12) LW(wAd,wp0,13) LW(wAe,wp0,14) LW(wAf,wp0,15)
    LW(wB0,wp1,0)  LW(wB1,wp1,1)  LW(wB2,wp1,2)  LW(wB3,wp1,3)
    LW(wB4,wp1,4)  LW(wB5,wp1,5)  LW(wB6,wp1,6)  LW(wB7,wp1,7)
    LW(wB8,wp1,8)  LW(wB9,wp1,9)  LW(wBa,wp1,10) LW(wBb,wp1,11)
    LW(wBc,wp1,12) LW(wBd,wp1,13) LW(wBe,wp1,14) LW(wBf,wp1,15)
    #undef LW
  }
  if (t < 256){ h32[t] = 0.f; h16[t] = (__fp16)0.f; }
  __syncthreads();

  // ---------------- 64-step scan ----------------
  const h8* hch = (const h8*)(h16 + 128*j);   // this thread's 128-f16 half
  for (int s=0;s<64;++s){
    const float gi_s = (float)gi16[s*768 + t];
    float a0 = 0.f, a1 = 0.f;          // partials for rows 2p, 2p+1
    #define DOTC(c, W0, W1) { const h8 hv = hch[c]; \
      a0=FD(P0(W0),P0(hv),a0); a1=FD(P0(W1),P0(hv),a1); \
      a0=FD(P1(W0),P1(hv),a0); a1=FD(P1(W1),P1(hv),a1); \
      a0=FD(P2(W0),P2(hv),a0); a1=FD(P2(W1),P2(hv),a1); \
      a0=FD(P3(W0),P3(hv),a0); a1=FD(P3(W1),P3(hv),a1); }
    DOTC(0,wA0,wB0)   DOTC(1,wA1,wB1)   DOTC(2,wA2,wB2)   DOTC(3,wA3,wB3)
    DOTC(4,wA4,wB4)   DOTC(5,wA5,wB5)   DOTC(6,wA6,wB6)   DOTC(7,wA7,wB7)
    DOTC(8,wA8,wB8)   DOTC(9,wA9,wB9)   DOTC(10,wAa,wBa)  DOTC(11,wAb,wBb)
    DOTC(12,wAc,wBc)  DOTC(13,wAd,wBd)  DOTC(14,wAe,wBe)  DOTC(15,wAf,wBf)
    #undef DOTC
    // thread j keeps partial of row 2p+j, sends the other
    const float keep = j ? a1 : a0;
    const float send = j ? a0 : a1;
    const float acc  = keep + __shfl_xor(send, 1) + bh_t;   // full dot row t
    if (t < 512) pre[t] = gi_s + acc;        // r,z pre-activations
    else       { pre[t] = gi_s; hn[t-512] = acc; }   // i_n and hn separate
    __syncthreads();
    if (t < 256){
      const float r  = sigm(pre[t]);
      const float z  = sigm(pre[256+t]);
      const float n  = tanhf(pre[512+t] + r*hn[t]);
      const float hv = (1.f - z)*n + z*h32[t];
      h32[t] = hv;
      h16[t] = (__fp16)hv;
    }
    __syncthreads();
  }

  // ---------------- attention -> fuse -> lin (h_enc == h32) ------------
  if (t < 128){
    const float4* wr = (const float4*)(aw + t*256);
    const float4* h4p = (const float4*)h32;
    float acc = ab[t];
    #pragma unroll 8
    for (int k=0;k<64;++k) acc += dot4(wr[k], h4p[k]);
    f0[t] = ws[WS_IMG + t] * sigm(acc);
  }
  __syncthreads();
  if (t < 256){
    const float4* wr = (const float4*)(lw + t*128);
    const float4* h4p = (const float4*)f0;
    float acc = lb[t];
    #pragma unroll 8
    for (int k=0;k<32;++k) acc += dot4(wr[k], h4p[k]);
    ws[WS_FUSED + t] = fmaxf(acc, 0.f);
  }
}

// ------------------------------------------------------------------- K3
__global__ __launch_bounds__(256) void a3c_post(
    const float* __restrict__ lwi, const float* __restrict__ lbi,
    const float* __restrict__ cx,
    const float* __restrict__ cw,  const float* __restrict__ acw,
    float* __restrict__ ws, float* __restrict__ out)
{
  const int p = blockIdx.x;            // 0..3, owns 64 LSTM units
  const int t = threadIdx.x;
  __shared__ __align__(16) float fused_lds[256];
  __shared__ float gv[256];
  __shared__ float hh[64];
  fused_lds[t] = ws[WS_FUSED + t];
  __syncthreads();
  const int g = t>>6, ul = t&63;
  const int R = (g<<8) + p*64 + ul;
  const float4* wr = (const float4*)(lwi + R*256);
  const float4* f4p = (const float4*)fused_lds;
  float acc = ws[WS_GATESH + R] + lbi[R];
  #pragma unroll 8
  for (int k=0;k<64;++k) acc += dot4(wr[k], f4p[k]);
  gv[t] = acc;
  __syncthreads();
  if (t < 64){
    const int u2 = p*64 + t;
    const float iv = gv[t], fv = gv[64+t], gg = gv[128+t], ov = gv[192+t];
    const float c = sigm(fv)*cx[u2] + sigm(iv)*tanhf(gg);
    const float h = sigm(ov)*tanhf(c);
    out[5   + u2] = h;
    out[261 + u2] = c;
    hh[t] = h;
  }
  __syncthreads();
  if (t < 64){
    #pragma unroll
    for (int o=0;o<5;++o){
      const float* wrow = (o==0) ? cw : (acw + (o-1)*288);
      float pr = hh[t]*wrow[p*64 + t];
      #pragma unroll
      for (int off=32; off; off>>=1) pr += __shfl_down(pr, off, 64);
      if (t == 0) atomicAdd(out + o, pr);
    }
  }
}

extern "C" void kernel_launch(void* const* d_in, const int* in_sizes, int n_in,
                              void* d_out, int out_size, void* d_ws, size_t ws_size,
                              hipStream_t stream) {
  (void)in_sizes; (void)n_in; (void)out_size; (void)ws_size;
  const float* x    = (const float*)d_in[0];
  const int*   inst = (const int*)  d_in[1];
  const int*   tx   = (const int*)  d_in[2];
  const float* hx   = (const float*)d_in[3];
  const float* cx   = (const float*)d_in[4];
  const float* i1w  = (const float*)d_in[5];
  const float* i1b  = (const float*)d_in[6];
  const float* i2w  = (const float*)d_in[7];
  const float* i2b  = (const float*)d_in[8];
  const float* i3w  = (const float*)d_in[9];
  const float* i3b  = (const float*)d_in[10];
  const float* emb  = (const float*)d_in[11];
  const float* gwi  = (const float*)d_in[12];
  const float* gwh  = (const float*)d_in[13];
  const float* gbi  = (const float*)d_in[14];
  const float* gbh  = (const float*)d_in[15];
  const float* aw   = (const float*)d_in[16];
  const float* ab   = (const float*)d_in[17];
  const float* temb = (const float*)d_in[18];
  const float* lw   = (const float*)d_in[19];
  const float* lb   = (const float*)d_in[20];
  const float* lwi  = (const float*)d_in[21];
  const float* lwh  = (const float*)d_in[22];
  const float* lbi  = (const float*)d_in[23];
  const float* lbh  = (const float*)d_in[24];
  const float* cw   = (const float*)d_in[25];
  const float* cb   = (const float*)d_in[26];
  const float* acw  = (const float*)d_in[27];
  const float* acb  = (const float*)d_in[28];
  float* ws  = (float*)d_ws;
  float* out = (float*)d_out;

  a3c_pre <<<6, 256, 0, stream>>>(x, i1w, i1b, i2w, i2b, i3w, i3b,
                                  hx, lwh, lbh, tx, temb, cw, cb, acw, acb,
                                  ws, out);
  a3c_scan<<<1, 768, 0, stream>>>(inst, emb, gwi, gwh, gbi, gbh,
                                  aw, ab, lw, lb, ws);
  a3c_post<<<4, 256, 0, stream>>>(lwi, lbi, cx, cw, acw, ws, out);
}

// Round 8
// 147.599 us; speedup vs baseline: 1.0725x; 1.0725x over previous
//
#include <hip/hip_runtime.h>
#include <math.h>

// ---------------------------------------------------------------------------
// A3C_LSTM_GA forward, batch=1.
// R8: 8-worker GRU scan co-located on ONE XCD (shared L2 -> fast data-flag
// sync), R1's proven no-spill per-CU compute (256 thr, 96 fp32 weight regs).
//   K1 a3c_init (65 blocks): sentinel-fill h slots + WS_IMG, zero sync cells
//   K2 a3c_scan (126 blocks x 256):
//        b<120   candidates: XCC_ID-based selection -> 8 workers on one XCD
//                 worker r: GRU rows for units [32r,32r+32); per-step
//                 data-as-flag h exchange via agent atomics in shared L2;
//                 worker 0 then does attention->fuse->lin
//        b=120   image MLP 400->128->128->128 -> WS_IMG (astore, sentinel'd)
//        b=121-4 gates_h = hx@lstm_wh.T+lbh
//        b=125   head-bias init out[0..4]
//   K3 a3c_post (4 blocks x 256): LSTM gates -> h/c -> head atomicAdd
// ---------------------------------------------------------------------------

#define SENT_U 0xFFC0DEADu  // NaN pattern; h/relu outputs can never be NaN

// ws layout (float offsets)
#define WS_HBUF   0        // 65*256; slot s+1 = h after step s
#define WS_CNT    16640    // 16 ints: per-XCD candidate arrival counters
#define WS_DESIG  16656    // int: designated XCD (-1 until set)
#define WS_WTK    16657    // int: worker ticket
#define WS_IMG    16660    // 128 (sentinel-initialized)
#define WS_GATESH 16788    // 1024
#define WS_FUSED  17812    // 256   (total 18068 floats = 72.3 KB)

__device__ __forceinline__ float dot4(const float4 a, const float4 b){
  return a.x*b.x + a.y*b.y + a.z*b.z + a.w*b.w;
}
__device__ __forceinline__ float sigm(float x){ return 1.f/(1.f+expf(-x)); }
__device__ __forceinline__ float aload(const float* p){
  return __hip_atomic_load(p, __ATOMIC_RELAXED, __HIP_MEMORY_SCOPE_AGENT);
}
__device__ __forceinline__ void astore(float* p, float v){
  __hip_atomic_store(p, v, __ATOMIC_RELAXED, __HIP_MEMORY_SCOPE_AGENT);
}

// ------------------------------------------------------------------- K1
__global__ __launch_bounds__(256) void a3c_init(float* __restrict__ ws){
  const int b = blockIdx.x, t = threadIdx.x;
  if (b < 64){
    ((unsigned*)(ws + WS_HBUF + 256))[b*256 + t] = SENT_U;   // slots 1..64
  } else {
    if (t < 128)               ((unsigned*)(ws + WS_IMG))[t] = SENT_U;
    else if (t < 144)          ((int*)(ws + WS_CNT))[t-128] = 0;
    else if (t == 144)         ((int*)(ws + WS_DESIG))[0] = -1;
    else if (t == 145)         ((int*)(ws + WS_WTK))[0] = 0;
  }
}

// ------------------------------------------------------------------- K2
__global__ __launch_bounds__(256) void a3c_scan(
    const int*   __restrict__ inst, const float* __restrict__ emb,
    const float* __restrict__ gwi,  const float* __restrict__ gwh,
    const float* __restrict__ gbi,  const float* __restrict__ gbh,
    const float* __restrict__ aw,   const float* __restrict__ ab,
    const float* __restrict__ lw,   const float* __restrict__ lb,
    const float* __restrict__ x,
    const float* __restrict__ i1w,  const float* __restrict__ i1b,
    const float* __restrict__ i2w,  const float* __restrict__ i2b,
    const float* __restrict__ i3w,  const float* __restrict__ i3b,
    const float* __restrict__ hx,   const float* __restrict__ lwh,
    const float* __restrict__ lbh,
    const int*   __restrict__ tx,   const float* __restrict__ temb,
    const float* __restrict__ cw,   const float* __restrict__ cb,
    const float* __restrict__ acw,  const float* __restrict__ acb,
    float* __restrict__ ws, float* __restrict__ out)
{
  const int b = blockIdx.x;
  const int t = threadIdx.x;

  if (b >= 120){
    // ----------------------------------------------- pre-roles (no sync)
    if (b == 120){
      // image MLP 400 -> 128 -> 128 -> 128 -> WS_IMG (astore: data-as-flag)
      __shared__ __align__(16) float x_lds[400];
      __shared__ __align__(16) float h1[128];
      __shared__ __align__(16) float h2s[128];
      x_lds[t] = x[t];
      if (t < 144) x_lds[256+t] = x[256+t];
      __syncthreads();
      {
        const int o = t>>1, half = t&1;
        const float4* wr = (const float4*)(i1w + o*400 + half*200);
        const float4* xr = (const float4*)(x_lds + half*200);
        float acc = 0.f;
        #pragma unroll 5
        for (int k=0;k<50;++k) acc += dot4(wr[k], xr[k]);
        acc += __shfl_down(acc, 1, 2);
        if (half == 0) h1[o] = fmaxf(acc + i1b[o], 0.f);
      }
      __syncthreads();
      if (t < 128){
        const float4* wr = (const float4*)(i2w + t*128);
        const float4* h4 = (const float4*)h1;
        float acc = i2b[t];
        #pragma unroll 8
        for (int k=0;k<32;++k) acc += dot4(wr[k], h4[k]);
        h2s[t] = fmaxf(acc, 0.f);
      }
      __syncthreads();
      if (t < 128){
        const float4* wr = (const float4*)(i3w + t*128);
        const float4* h4 = (const float4*)h2s;
        float acc = i3b[t];
        #pragma unroll 8
        for (int k=0;k<32;++k) acc += dot4(wr[k], h4[k]);
        astore(ws + WS_IMG + t, fmaxf(acc, 0.f));
      }
    } else if (b == 125){
      // out[0..4] = bias + time-embedding partial of the heads
      if (t < 64){
        float tv = 0.f;
        if (t < 32) tv = temb[tx[0]*32 + t];
        #pragma unroll
        for (int o=0;o<5;++o){
          const float* wrow = (o==0) ? cw : (acw + (o-1)*288);
          float pr = (t < 32) ? tv*wrow[256+t] : 0.f;
          #pragma unroll
          for (int off=16; off; off>>=1) pr += __shfl_down(pr, off, 32);
          if (t == 0) out[o] = pr + ((o==0) ? cb[0] : acb[o-1]);
        }
      }
    } else {
      // b in 121..124: gates_h = hx @ lstm_wh.T + lstm_bh
      __shared__ __align__(16) float hx_lds[256];
      hx_lds[t] = hx[t];
      __syncthreads();
      const int R = (b-121)*256 + t;
      const float4* wr = (const float4*)(lwh + R*256);
      const float4* h4 = (const float4*)hx_lds;
      float acc = lbh[R];
      #pragma unroll 8
      for (int k=0;k<64;++k) acc += dot4(wr[k], h4[k]);
      ws[WS_GATESH + R] = acc;
    }
    return;
  }

  // ----------------------------------------------- worker selection
  __shared__ int s_role;
  if (t == 0){
    unsigned xcc;
    asm volatile("s_getreg_b32 %0, hwreg(20, 0, 4)" : "=s"(xcc));
    xcc &= 7u;
    int* cnt   = (int*)(ws + WS_CNT);
    int* desig = (int*)(ws + WS_DESIG);
    int* wtk   = (int*)(ws + WS_WTK);
    const int arr = __hip_atomic_fetch_add(&cnt[xcc], 1, __ATOMIC_RELAXED,
                                           __HIP_MEMORY_SCOPE_AGENT);
    if (arr == 7){
      int exp = -1;
      __hip_atomic_compare_exchange_strong(desig, &exp, (int)xcc,
          __ATOMIC_RELEASE, __ATOMIC_RELAXED, __HIP_MEMORY_SCOPE_AGENT);
    }
    int d;
    while ((d = __hip_atomic_load(desig, __ATOMIC_ACQUIRE,
                                  __HIP_MEMORY_SCOPE_AGENT)) < 0)
      __builtin_amdgcn_s_sleep(2);
    int role = -1;
    if ((int)xcc == d){
      const int tk = __hip_atomic_fetch_add(wtk, 1, __ATOMIC_RELAXED,
                                            __HIP_MEMORY_SCOPE_AGENT);
      if (tk < 8) role = tk;
    }
    s_role = role;
  }
  __syncthreads();
  const int r = s_role;
  if (r < 0) return;

  // ----------------------------------------------- GRU worker (R1-proven)
  __shared__ __align__(16) float h_lds[256];
  __shared__ float gi_lds[64*96];                  // [step][local row]
  __shared__ __align__(16) float emb_lds[64*32];
  __shared__ __align__(16) float f0[128];
  const int u   = t >> 3;       // local unit 0..31
  const int sub = t & 7;        // column slice 0..7
  const int U   = r*32 + u;     // global unit

  float4 wv0[8], wv1[8], wv2[8];          // 96 fp32 regs (no-spill at 256thr)
  {
    const float4* p0 = (const float4*)(gwh + (0*256 + U)*256 + sub*32);
    const float4* p1 = (const float4*)(gwh + (1*256 + U)*256 + sub*32);
    const float4* p2 = (const float4*)(gwh + (2*256 + U)*256 + sub*32);
    #pragma unroll
    for (int k=0;k<8;++k){ wv0[k]=p0[k]; wv1[k]=p1[k]; wv2[k]=p2[k]; }
  }
  const float bh0 = gbh[U], bh1 = gbh[256+U], bh2 = gbh[512+U];

  for (int i=t; i<64*32; i+=256)
    emb_lds[i] = emb[inst[i>>5]*32 + (i&31)];
  h_lds[t] = 0.f;
  __syncthreads();

  if (t < 192){
    const int lr = t>>1, half = t&1;
    const int g = lr>>5, ul = lr&31;
    const int grow = (g<<8) + r*32 + ul;
    float4 wi[8];
    const float4* wip = (const float4*)(gwi + grow*32);
    #pragma unroll
    for (int k=0;k<8;++k) wi[k]=wip[k];
    const float bi = gbi[grow];
    for (int s=half*32; s<half*32+32; ++s){
      const float4* e4 = (const float4*)(emb_lds + s*32);
      float acc = bi;
      #pragma unroll
      for (int k=0;k<8;++k) acc += dot4(wi[k], e4[k]);
      gi_lds[s*96 + lr] = acc;
    }
  }
  __syncthreads();

  float* hb = ws + WS_HBUF;
  for (int s=0; s<64; ++s){
    const float4* h4 = (const float4*)(h_lds + sub*32);
    float p0=0.f, p1=0.f, p2=0.f;
    #pragma unroll
    for (int k=0;k<8;++k){
      const float4 h = h4[k];
      p0 += dot4(wv0[k], h);
      p1 += dot4(wv1[k], h);
      p2 += dot4(wv2[k], h);
    }
    #pragma unroll
    for (int off=4; off; off>>=1){
      p0 += __shfl_down(p0, off, 8);
      p1 += __shfl_down(p1, off, 8);
      p2 += __shfl_down(p2, off, 8);
    }
    const float h_old = h_lds[U];
    if (sub == 0){
      const float* gis = gi_lds + s*96;
      const float rr = sigm(gis[u]      + p0 + bh0);
      const float zz = sigm(gis[32 + u] + p1 + bh1);
      const float nn = tanhf(gis[64 + u] + rr*(p2 + bh2));
      astore(&hb[(s+1)*256 + U], (1.f - zz)*nn + zz*h_old);
    }
    __syncthreads();   // order our stores before our polls
    float v;
    do { v = aload(&hb[(s+1)*256 + t]); } while (__float_as_uint(v) == SENT_U);
    h_lds[t] = v;
    __syncthreads();
  }

  // ----------------------------------------------- worker 0: attn tail
  if (r == 0){
    float im = 0.f;
    if (t < 128){
      do { im = aload(ws + WS_IMG + t); } while (__float_as_uint(im) == SENT_U);
      const float4* wr = (const float4*)(aw + t*256);
      const float4* h4 = (const float4*)h_lds;
      float acc = ab[t];
      #pragma unroll 8
      for (int k=0;k<64;++k) acc += dot4(wr[k], h4[k]);
      f0[t] = im * sigm(acc);
    }
    __syncthreads();
    {
      const float4* wr = (const float4*)(lw + t*128);
      const float4* h4 = (const float4*)f0;
      float acc = lb[t];
      #pragma unroll 8
      for (int k=0;k<32;++k) acc += dot4(wr[k], h4[k]);
      ws[WS_FUSED + t] = fmaxf(acc, 0.f);
    }
  }
}

// ------------------------------------------------------------------- K3
__global__ __launch_bounds__(256) void a3c_post(
    const float* __restrict__ lwi, const float* __restrict__ lbi,
    const float* __restrict__ cx,
    const float* __restrict__ cw,  const float* __restrict__ acw,
    float* __restrict__ ws, float* __restrict__ out)
{
  const int p = blockIdx.x;            // 0..3, owns 64 LSTM units
  const int t = threadIdx.x;
  __shared__ __align__(16) float fused_lds[256];
  __shared__ float gv[256];
  __shared__ float hh[64];
  fused_lds[t] = ws[WS_FUSED + t];
  __syncthreads();
  const int g = t>>6, ul = t&63;
  const int R = (g<<8) + p*64 + ul;
  const float4* wr = (const float4*)(lwi + R*256);
  const float4* f4 = (const float4*)fused_lds;
  float acc = ws[WS_GATESH + R] + lbi[R];
  #pragma unroll 8
  for (int k=0;k<64;++k) acc += dot4(wr[k], f4[k]);
  gv[t] = acc;
  __syncthreads();
  if (t < 64){
    const int u2 = p*64 + t;
    const float iv = gv[t], fv = gv[64+t], gg = gv[128+t], ov = gv[192+t];
    const float c = sigm(fv)*cx[u2] + sigm(iv)*tanhf(gg);
    const float h = sigm(ov)*tanhf(c);
    out[5   + u2] = h;
    out[261 + u2] = c;
    hh[t] = h;
  }
  __syncthreads();
  if (t < 64){
    #pragma unroll
    for (int o=0;o<5;++o){
      const float* wrow = (o==0) ? cw : (acw + (o-1)*288);
      float pr = hh[t]*wrow[p*64 + t];
      #pragma unroll
      for (int off=32; off; off>>=1) pr += __shfl_down(pr, off, 64);
      if (t == 0) atomicAdd(out + o, pr);
    }
  }
}

extern "C" void kernel_launch(void* const* d_in, const int* in_sizes, int n_in,
                              void* d_out, int out_size, void* d_ws, size_t ws_size,
                              hipStream_t stream) {
  (void)in_sizes; (void)n_in; (void)out_size; (void)ws_size;
  const float* x    = (const float*)d_in[0];
  const int*   inst = (const int*)  d_in[1];
  const int*   tx   = (const int*)  d_in[2];
  const float* hx   = (const float*)d_in[3];
  const float* cx   = (const float*)d_in[4];
  const float* i1w  = (const float*)d_in[5];
  const float* i1b  = (const float*)d_in[6];
  const float* i2w  = (const float*)d_in[7];
  const float* i2b  = (const float*)d_in[8];
  const float* i3w  = (const float*)d_in[9];
  const float* i3b  = (const float*)d_in[10];
  const float* emb  = (const float*)d_in[11];
  const float* gwi  = (const float*)d_in[12];
  const float* gwh  = (const float*)d_in[13];
  const float* gbi  = (const float*)d_in[14];
  const float* gbh  = (const float*)d_in[15];
  const float* aw   = (const float*)d_in[16];
  const float* ab   = (const float*)d_in[17];
  const float* temb = (const float*)d_in[18];
  const float* lw   = (const float*)d_in[19];
  const float* lb   = (const float*)d_in[20];
  const float* lwi  = (const float*)d_in[21];
  const float* lwh  = (const float*)d_in[22];
  const float* lbi  = (const float*)d_in[23];
  const float* lbh  = (const float*)d_in[24];
  const float* cw   = (const float*)d_in[25];
  const float* cb   = (const float*)d_in[26];
  const float* acw  = (const float*)d_in[27];
  const float* acb  = (const float*)d_in[28];
  float* ws  = (float*)d_ws;
  float* out = (float*)d_out;

  a3c_init<<<65, 256, 0, stream>>>(ws);
  a3c_scan<<<126, 256, 0, stream>>>(inst, emb, gwi, gwh, gbi, gbh,
                                    aw, ab, lw, lb,
                                    x, i1w, i1b, i2w, i2b, i3w, i3b,
                                    hx, lwh, lbh, tx, temb, cw, cb, acw, acb,
                                    ws, out);
  a3c_post<<<4, 256, 0, stream>>>(lwi, lbi, cx, cw, acw, ws, out);
}

// Round 9
// 143.928 us; speedup vs baseline: 1.0999x; 1.0255x over previous
//
#include <hip/hip_runtime.h>
#include <math.h>

// ---------------------------------------------------------------------------
// A3C_LSTM_GA forward, batch=1.  R9: single-CU GRU scan, zero cross-WG sync.
//  K1 a3c_pre (594 blocks x 256):
//     b0      image MLP -> ws[WS_IMG]
//     b1-4    gates_h = hx@lstm_wh.T + lbh -> ws[WS_GATESH]
//     b5      head-bias init out[0..4]
//     b6-197  gi[s][row] = gru_wi@emb_s + gbi  (f32) -> ws[WS_GI]
//     b198-485 regw: gwh cols[64,256) -> f16, per-thread fragment layout
//     b486-593 ldsw: gwh cols[0,64)  -> f16, [row][72-stride] padded layout
//  K2 a3c_scan (1 block x 1024): quad q owns rows {3q,3q+1,3q+2}; lane i of
//     quad holds 18 NAMED h8 reg fragments (72 VGPR) for cols 64+(4k+i)*8;
//     LDS part cols {i,i+4}*8; per step: 96 dot2 + quad shfl-reduce ->
//     pre[] -> 256 threads gate math.  gi double-buffered from global.
//     Attention+fuse+lin fused at end.
//  K3 a3c_post (4 blocks x 256): LSTM -> h/c -> head atomicAdd partials
// ---------------------------------------------------------------------------

typedef __fp16 h2 __attribute__((ext_vector_type(2)));
typedef __fp16 h8 __attribute__((ext_vector_type(8)));

// ws float offsets
#define WS_IMG    0        // 128
#define WS_GATESH 128      // 1024
#define WS_FUSED  1152     // 256
#define WS_GI     1408     // 64*768 f32
#define WS_REGW   50560    // 147456 f16 (73728 f32 slots)
#define WS_LDSW   124288   // 768*72 f16 (27648 f32 slots)  end=151936 (608KB)

__device__ __forceinline__ float dot4(const float4 a, const float4 b){
  return a.x*b.x + a.y*b.y + a.z*b.z + a.w*b.w;
}
__device__ __forceinline__ float sigm(float x){ return 1.f/(1.f+expf(-x)); }

#define P0(v) __builtin_shufflevector(v,v,0,1)
#define P1(v) __builtin_shufflevector(v,v,2,3)
#define P2(v) __builtin_shufflevector(v,v,4,5)
#define P3(v) __builtin_shufflevector(v,v,6,7)
#define PK(a,b) __builtin_amdgcn_cvt_pkrtz(a,b)
#define FD(w,e,acc) __builtin_amdgcn_fdot2(w,e,acc,false)

// ------------------------------------------------------------------- K1
__global__ __launch_bounds__(256) void a3c_pre(
    const float* __restrict__ x,
    const float* __restrict__ i1w, const float* __restrict__ i1b,
    const float* __restrict__ i2w, const float* __restrict__ i2b,
    const float* __restrict__ i3w, const float* __restrict__ i3b,
    const float* __restrict__ hx,  const float* __restrict__ lwh,
    const float* __restrict__ lbh,
    const int*   __restrict__ tx,  const float* __restrict__ temb,
    const float* __restrict__ cw,  const float* __restrict__ cb,
    const float* __restrict__ acw, const float* __restrict__ acb,
    const int*   __restrict__ inst, const float* __restrict__ emb,
    const float* __restrict__ gwi,  const float* __restrict__ gbi,
    const float* __restrict__ gwh,
    float* __restrict__ ws, float* __restrict__ out)
{
  const int b = blockIdx.x;
  const int t = threadIdx.x;

  if (b == 0) {
    // image MLP 400 -> 128 -> 128 -> 128
    __shared__ __align__(16) float x_lds[400];
    __shared__ __align__(16) float h1[128];
    __shared__ __align__(16) float h2s[128];
    x_lds[t] = x[t];
    if (t < 144) x_lds[256+t] = x[256+t];
    __syncthreads();
    {
      const int o = t>>1, half = t&1;
      const float4* wr = (const float4*)(i1w + o*400 + half*200);
      const float4* xr = (const float4*)(x_lds + half*200);
      float acc = 0.f;
      #pragma unroll 5
      for (int k=0;k<50;++k) acc += dot4(wr[k], xr[k]);
      acc += __shfl_down(acc, 1, 2);
      if (half == 0) h1[o] = fmaxf(acc + i1b[o], 0.f);
    }
    __syncthreads();
    if (t < 128){
      const float4* wr = (const float4*)(i2w + t*128);
      const float4* h4 = (const float4*)h1;
      float acc = i2b[t];
      #pragma unroll 8
      for (int k=0;k<32;++k) acc += dot4(wr[k], h4[k]);
      h2s[t] = fmaxf(acc, 0.f);
    }
    __syncthreads();
    if (t < 128){
      const float4* wr = (const float4*)(i3w + t*128);
      const float4* h4 = (const float4*)h2s;
      float acc = i3b[t];
      #pragma unroll 8
      for (int k=0;k<32;++k) acc += dot4(wr[k], h4[k]);
      ws[WS_IMG + t] = fmaxf(acc, 0.f);
    }

  } else if (b <= 4) {
    // gates_h = hx @ lstm_wh.T + lstm_bh
    __shared__ __align__(16) float hx_lds[256];
    hx_lds[t] = hx[t];
    __syncthreads();
    const int R = (b-1)*256 + t;
    const float4* wr = (const float4*)(lwh + R*256);
    const float4* h4 = (const float4*)hx_lds;
    float acc = lbh[R];
    #pragma unroll 8
    for (int k=0;k<64;++k) acc += dot4(wr[k], h4[k]);
    ws[WS_GATESH + R] = acc;

  } else if (b == 5) {
    // out[0..4] = bias + time-embedding partial of heads
    if (t < 64){
      float tv = 0.f;
      if (t < 32) tv = temb[tx[0]*32 + t];
      #pragma unroll
      for (int o=0;o<5;++o){
        const float* wrow = (o==0) ? cw : (acw + (o-1)*288);
        float pr = (t < 32) ? tv*wrow[256+t] : 0.f;
        #pragma unroll
        for (int off=16; off; off>>=1) pr += __shfl_down(pr, off, 32);
        if (t == 0) out[o] = pr + ((o==0) ? cb[0] : acb[o-1]);
      }
    }

  } else if (b < 198) {
    // gi[s][row] (f32): 192 blocks x 256 = 49152 = 64*768
    const int idx = (b-6)*256 + t;
    const int s = idx / 768;
    const int r = idx - s*768;
    const float4* wr = (const float4*)(gwi + r*32);
    const float4* er = (const float4*)(emb + inst[s]*32);
    float acc = gbi[r];
    #pragma unroll
    for (int k=0;k<8;++k) acc += dot4(wr[k], er[k]);
    ws[WS_GI + idx] = acc;

  } else if (b < 486) {
    // regw: 288 blocks x 256 = 73728 h2-pairs = 147456 f16
    const int d = (b-198)*256 + t;
    const int e = d*2;
    const int tt  = e / 144;  int rem = e - tt*144;
    const int rho = rem / 48; rem -= rho*48;
    const int k   = rem >> 3;
    const int el  = rem & 7;
    const int q = tt >> 2, i = tt & 3;
    const int row = 3*q + rho;
    const int col = 64 + ((k<<2)+i)*8 + el;
    ((h2*)(ws + WS_REGW))[d] = PK(gwh[row*256+col], gwh[row*256+col+1]);

  } else {
    // ldsw: 108 blocks x 256 = 27648 h2-pairs = 768 rows x 72 f16 (64 data+8 pad)
    const int d = (b-486)*256 + t;
    const int e = d*2;
    const int row = e / 72;
    const int col = e - row*72;
    float a0 = 0.f, a1 = 0.f;
    if (col < 64){ a0 = gwh[row*256+col]; a1 = gwh[row*256+col+1]; }
    ((h2*)(ws + WS_LDSW))[d] = PK(a0, a1);
  }
}

// ------------------------------------------------------------------- K2
__global__ __attribute__((amdgpu_flat_work_group_size(1024,1024),
                          amdgpu_waves_per_eu(4,4)))
void a3c_scan(
    const float* __restrict__ gbh,
    const float* __restrict__ aw,  const float* __restrict__ ab,
    const float* __restrict__ lnw, const float* __restrict__ lnb,
    float* __restrict__ ws)
{
  const int t = threadIdx.x;
  const int q = t >> 2, i = t & 3;
  const int r0 = 3*q, r1 = 3*q+1, r2 = 3*q+2;

  __shared__ __align__(16) __fp16 lw_[768*72];     // 110592 B
  __shared__ __align__(16) __fp16 h16[256];
  __shared__ float h32[256];
  __shared__ float pre[768];
  __shared__ float bhl[768];
  __shared__ float gil[2][768];
  __shared__ __align__(16) float f0[128];

  // stage LDS weights (pre-padded layout, linear copy)
  {
    const float4* src = (const float4*)(ws + WS_LDSW);
    float4* dst = (float4*)lw_;
    for (int n=t; n<6912; n+=1024) dst[n] = src[n];
  }
  if (t < 768){ bhl[t] = gbh[t]; gil[0][t] = ws[WS_GI + t]; }
  if (t < 256){ h16[t] = (__fp16)0.f; h32[t] = 0.f; }

  // 18 named h8 register fragments: cols 64+(4k+i)*8, rows r0..r2
  const h8* rw = (const h8*)(ws + WS_REGW) + t*18;
  const h8 W00=rw[0],  W01=rw[1],  W02=rw[2],  W03=rw[3],  W04=rw[4],  W05=rw[5];
  const h8 W10=rw[6],  W11=rw[7],  W12=rw[8],  W13=rw[9],  W14=rw[10], W15=rw[11];
  const h8 W20=rw[12], W21=rw[13], W22=rw[14], W23=rw[15], W24=rw[16], W25=rw[17];
  __syncthreads();

  int cur = 0;
  for (int s=0; s<64; ++s){
    float gnx = 0.f;
    if (t < 768) gnx = ws[WS_GI + ((s<63)?(s+1):63)*768 + t];  // prefetch

    float p0=0.f, p1=0.f, p2=0.f;
    // ---- LDS part: cols {i,i+4}*8
    {
      const h8 hva = *(const h8*)(h16 + (i<<3));
      const h8 hvb = *(const h8*)(h16 + ((i+4)<<3));
      #define LBLK(RR, PA) { \
        const h8 wa = *(const h8*)(lw_ + (RR)*72 + (i<<3)); \
        const h8 wb = *(const h8*)(lw_ + (RR)*72 + ((i+4)<<3)); \
        PA=FD(P0(wa),P0(hva),PA); PA=FD(P1(wa),P1(hva),PA); \
        PA=FD(P2(wa),P2(hva),PA); PA=FD(P3(wa),P3(hva),PA); \
        PA=FD(P0(wb),P0(hvb),PA); PA=FD(P1(wb),P1(hvb),PA); \
        PA=FD(P2(wb),P2(hvb),PA); PA=FD(P3(wb),P3(hvb),PA); }
      LBLK(r0,p0) LBLK(r1,p1) LBLK(r2,p2)
      #undef LBLK
    }
    // ---- reg part: k=0..5, h chunk 8+4k+i
    #define RBLK(K) { \
      const h8 hv = *(const h8*)(h16 + ((8+((K)<<2)+i)<<3)); \
      p0=FD(P0(W0##K),P0(hv),p0); p0=FD(P1(W0##K),P1(hv),p0); \
      p0=FD(P2(W0##K),P2(hv),p0); p0=FD(P3(W0##K),P3(hv),p0); \
      p1=FD(P0(W1##K),P0(hv),p1); p1=FD(P1(W1##K),P1(hv),p1); \
      p1=FD(P2(W1##K),P2(hv),p1); p1=FD(P3(W1##K),P3(hv),p1); \
      p2=FD(P0(W2##K),P0(hv),p2); p2=FD(P1(W2##K),P1(hv),p2); \
      p2=FD(P2(W2##K),P2(hv),p2); p2=FD(P3(W2##K),P3(hv),p2); }
    RBLK(0) RBLK(1) RBLK(2) RBLK(3) RBLK(4) RBLK(5)
    #undef RBLK

    // quad reduce (lanes 4g..4g+3)
    p0 += __shfl_xor(p0,1); p0 += __shfl_xor(p0,2);
    p1 += __shfl_xor(p1,1); p1 += __shfl_xor(p1,2);
    p2 += __shfl_xor(p2,1); p2 += __shfl_xor(p2,2);
    if (i < 3){
      const int row = 3*q + i;
      const float pv = (i==0) ? p0 : ((i==1) ? p1 : p2);
      pre[row] = pv + bhl[row];
    }
    if (t < 768) gil[cur^1][t] = gnx;
    __syncthreads();
    if (t < 256){
      const float rr = sigm(gil[cur][t]       + pre[t]);
      const float zz = sigm(gil[cur][256 + t] + pre[256 + t]);
      const float nn = tanhf(gil[cur][512 + t] + rr*pre[512 + t]);
      const float hv = (1.f - zz)*nn + zz*h32[t];
      h32[t] = hv;
      h16[t] = (__fp16)hv;
    }
    cur ^= 1;
    __syncthreads();
  }

  // ---- attention -> fuse -> lin (h_enc == h32)
  if (t < 128){
    const float4* wr = (const float4*)(aw + t*256);
    const float4* h4 = (const float4*)h32;
    float acc = ab[t];
    #pragma unroll 8
    for (int k=0;k<64;++k) acc += dot4(wr[k], h4[k]);
    f0[t] = ws[WS_IMG + t] * sigm(acc);
  }
  __syncthreads();
  if (t < 256){
    const float4* wr = (const float4*)(lnw + t*128);
    const float4* h4 = (const float4*)f0;
    float acc = lnb[t];
    #pragma unroll 8
    for (int k=0;k<32;++k) acc += dot4(wr[k], h4[k]);
    ws[WS_FUSED + t] = fmaxf(acc, 0.f);
  }
}

// ------------------------------------------------------------------- K3
__global__ __launch_bounds__(256) void a3c_post(
    const float* __restrict__ lwi, const float* __restrict__ lbi,
    const float* __restrict__ cx,
    const float* __restrict__ cw,  const float* __restrict__ acw,
    float* __restrict__ ws, float* __restrict__ out)
{
  const int p = blockIdx.x;            // 0..3, owns 64 LSTM units
  const int t = threadIdx.x;
  __shared__ __align__(16) float fused_lds[256];
  __shared__ float gv[256];
  __shared__ float hh[64];
  fused_lds[t] = ws[WS_FUSED + t];
  __syncthreads();
  const int g = t>>6, ul = t&63;
  const int R = (g<<8) + p*64 + ul;
  const float4* wr = (const float4*)(lwi + R*256);
  const float4* f4 = (const float4*)fused_lds;
  float acc = ws[WS_GATESH + R] + lbi[R];
  #pragma unroll 8
  for (int k=0;k<64;++k) acc += dot4(wr[k], f4[k]);
  gv[t] = acc;
  __syncthreads();
  if (t < 64){
    const int u2 = p*64 + t;
    const float iv = gv[t], fv = gv[64+t], gg = gv[128+t], ov = gv[192+t];
    const float c = sigm(fv)*cx[u2] + sigm(iv)*tanhf(gg);
    const float h = sigm(ov)*tanhf(c);
    out[5   + u2] = h;
    out[261 + u2] = c;
    hh[t] = h;
  }
  __syncthreads();
  if (t < 64){
    #pragma unroll
    for (int o=0;o<5;++o){
      const float* wrow = (o==0) ? cw : (acw + (o-1)*288);
      float pr = hh[t]*wrow[p*64 + t];
      #pragma unroll
      for (int off=32; off; off>>=1) pr += __shfl_down(pr, off, 64);
      if (t == 0) atomicAdd(out + o, pr);
    }
  }
}

extern "C" void kernel_launch(void* const* d_in, const int* in_sizes, int n_in,
                              void* d_out, int out_size, void* d_ws, size_t ws_size,
                              hipStream_t stream) {
  (void)in_sizes; (void)n_in; (void)out_size; (void)ws_size;
  const float* x    = (const float*)d_in[0];
  const int*   inst = (const int*)  d_in[1];
  const int*   tx   = (const int*)  d_in[2];
  const float* hx   = (const float*)d_in[3];
  const float* cx   = (const float*)d_in[4];
  const float* i1w  = (const float*)d_in[5];
  const float* i1b  = (const float*)d_in[6];
  const float* i2w  = (const float*)d_in[7];
  const float* i2b  = (const float*)d_in[8];
  const float* i3w  = (const float*)d_in[9];
  const float* i3b  = (const float*)d_in[10];
  const float* emb  = (const float*)d_in[11];
  const float* gwi  = (const float*)d_in[12];
  const float* gwh  = (const float*)d_in[13];
  const float* gbi  = (const float*)d_in[14];
  const float* gbh  = (const float*)d_in[15];
  const float* aw   = (const float*)d_in[16];
  const float* ab   = (const float*)d_in[17];
  const float* temb = (const float*)d_in[18];
  const float* lnw  = (const float*)d_in[19];
  const float* lnb  = (const float*)d_in[20];
  const float* lwi  = (const float*)d_in[21];
  const float* lwh  = (const float*)d_in[22];
  const float* lbi  = (const float*)d_in[23];
  const float* lbh  = (const float*)d_in[24];
  const float* cw   = (const float*)d_in[25];
  const float* cb   = (const float*)d_in[26];
  const float* acw  = (const float*)d_in[27];
  const float* acb  = (const float*)d_in[28];
  float* ws  = (float*)d_ws;
  float* out = (float*)d_out;

  a3c_pre <<<594, 256, 0, stream>>>(x, i1w, i1b, i2w, i2b, i3w, i3b,
                                    hx, lwh, lbh, tx, temb, cw, cb, acw, acb,
                                    inst, emb, gwi, gbi, gwh, ws, out);
  a3c_scan<<<1, 1024, 0, stream>>>(gbh, aw, ab, lnw, lnb, ws);
  a3c_post<<<4, 256, 0, stream>>>(lwi, lbi, cx, cw, acw, ws, out);
}

// Round 10
// 125.737 us; speedup vs baseline: 1.2590x; 1.1447x over previous
//
#include <hip/hip_runtime.h>
#include <math.h>

// ---------------------------------------------------------------------------
// A3C_LSTM_GA forward, batch=1.  R10: single-CU GRU scan; weights pinned in
// VGPRs via asm("" : "+v") so the compiler cannot rematerialize the loads
// (R9 showed remat-from-L2 = 2us/step).  Zero cross-WG sync.
//  K1 a3c_pre (582 blocks x 256):
//     b0      image MLP -> ws[WS_IMG]
//     b1-4    gates_h = hx@lstm_wh.T + lbh
//     b5      head-bias init out[0..4]
//     b6-197  gi[s][row] (f32) -> ws[WS_GI]
//     b198-581 regw: gwh -> f16 in per-thread fragment order
//  K2 a3c_scan (1 block x 1024): octet o owns rows [6o,6o+6); lane i holds
//     cols [32i,32i+32) as 24 pinned f4 fragments (96 VGPR).  Per step:
//     4 broadcast ds_read_b128 of h + 96 v_dot2 + 6 partial stores
//     (stride-9 pad); gate threads (256) sum 8 partials + gate math.
//  K3 a3c_post (4 blocks x 256): LSTM -> h/c -> head atomicAdd partials
// ---------------------------------------------------------------------------

typedef __fp16 h2 __attribute__((ext_vector_type(2)));
typedef __fp16 h8 __attribute__((ext_vector_type(8)));
typedef float  f4 __attribute__((ext_vector_type(4)));

// ws float offsets
#define WS_IMG    0        // 128
#define WS_GATESH 128      // 1024
#define WS_FUSED  1152     // 256
#define WS_GI     1408     // 64*768 f32
#define WS_REGW   50560    // 98304 float slots (196608 f16)  end=148864

__device__ __forceinline__ float dot4(const float4 a, const float4 b){
  return a.x*b.x + a.y*b.y + a.z*b.z + a.w*b.w;
}
__device__ __forceinline__ float sigm(float x){ return 1.f/(1.f+expf(-x)); }

#define P0(v) __builtin_shufflevector(v,v,0,1)
#define P1(v) __builtin_shufflevector(v,v,2,3)
#define P2(v) __builtin_shufflevector(v,v,4,5)
#define P3(v) __builtin_shufflevector(v,v,6,7)
#define PK(a,b) __builtin_amdgcn_cvt_pkrtz(a,b)
#define FD(w,e,acc) __builtin_amdgcn_fdot2(w,e,acc,false)

// ------------------------------------------------------------------- K1
__global__ __launch_bounds__(256) void a3c_pre(
    const float* __restrict__ x,
    const float* __restrict__ i1w, const float* __restrict__ i1b,
    const float* __restrict__ i2w, const float* __restrict__ i2b,
    const float* __restrict__ i3w, const float* __restrict__ i3b,
    const float* __restrict__ hx,  const float* __restrict__ lwh,
    const float* __restrict__ lbh,
    const int*   __restrict__ tx,  const float* __restrict__ temb,
    const float* __restrict__ cw,  const float* __restrict__ cb,
    const float* __restrict__ acw, const float* __restrict__ acb,
    const int*   __restrict__ inst, const float* __restrict__ emb,
    const float* __restrict__ gwi,  const float* __restrict__ gbi,
    const float* __restrict__ gwh,
    float* __restrict__ ws, float* __restrict__ out)
{
  const int b = blockIdx.x;
  const int t = threadIdx.x;

  if (b == 0) {
    // image MLP 400 -> 128 -> 128 -> 128
    __shared__ __align__(16) float x_lds[400];
    __shared__ __align__(16) float h1[128];
    __shared__ __align__(16) float h2s[128];
    x_lds[t] = x[t];
    if (t < 144) x_lds[256+t] = x[256+t];
    __syncthreads();
    {
      const int o = t>>1, half = t&1;
      const float4* wr = (const float4*)(i1w + o*400 + half*200);
      const float4* xr = (const float4*)(x_lds + half*200);
      float acc = 0.f;
      #pragma unroll 5
      for (int k=0;k<50;++k) acc += dot4(wr[k], xr[k]);
      acc += __shfl_down(acc, 1, 2);
      if (half == 0) h1[o] = fmaxf(acc + i1b[o], 0.f);
    }
    __syncthreads();
    if (t < 128){
      const float4* wr = (const float4*)(i2w + t*128);
      const float4* h4 = (const float4*)h1;
      float acc = i2b[t];
      #pragma unroll 8
      for (int k=0;k<32;++k) acc += dot4(wr[k], h4[k]);
      h2s[t] = fmaxf(acc, 0.f);
    }
    __syncthreads();
    if (t < 128){
      const float4* wr = (const float4*)(i3w + t*128);
      const float4* h4 = (const float4*)h2s;
      float acc = i3b[t];
      #pragma unroll 8
      for (int k=0;k<32;++k) acc += dot4(wr[k], h4[k]);
      ws[WS_IMG + t] = fmaxf(acc, 0.f);
    }

  } else if (b <= 4) {
    // gates_h = hx @ lstm_wh.T + lstm_bh
    __shared__ __align__(16) float hx_lds[256];
    hx_lds[t] = hx[t];
    __syncthreads();
    const int R = (b-1)*256 + t;
    const float4* wr = (const float4*)(lwh + R*256);
    const float4* h4 = (const float4*)hx_lds;
    float acc = lbh[R];
    #pragma unroll 8
    for (int k=0;k<64;++k) acc += dot4(wr[k], h4[k]);
    ws[WS_GATESH + R] = acc;

  } else if (b == 5) {
    // out[0..4] = bias + time-embedding partial of heads
    if (t < 64){
      float tv = 0.f;
      if (t < 32) tv = temb[tx[0]*32 + t];
      #pragma unroll
      for (int o=0;o<5;++o){
        const float* wrow = (o==0) ? cw : (acw + (o-1)*288);
        float pr = (t < 32) ? tv*wrow[256+t] : 0.f;
        #pragma unroll
        for (int off=16; off; off>>=1) pr += __shfl_down(pr, off, 32);
        if (t == 0) out[o] = pr + ((o==0) ? cb[0] : acb[o-1]);
      }
    }

  } else if (b < 198) {
    // gi[s][row] (f32): 192 blocks x 256 = 49152 = 64*768
    const int idx = (b-6)*256 + t;
    const int s = idx / 768;
    const int r = idx - s*768;
    const float4* wr = (const float4*)(gwi + r*32);
    const float4* er = (const float4*)(emb + inst[s]*32);
    float acc = gbi[r];
    #pragma unroll
    for (int k=0;k<8;++k) acc += dot4(wr[k], er[k]);
    ws[WS_GI + idx] = acc;

  } else {
    // regw: 384 blocks x 256 = 98304 h2 = 196608 f16, per-thread order:
    // thread tt = (octet o = tt>>3, lane i = tt&7) : rows 6o+rho (rho 0..5),
    // cols 32i + 8c + el (c 0..3, el 0..7); fragment index rho*4+c
    const int d = (b-198)*256 + t;      // h2 index
    const int e = d << 1;               // f16 index
    const int tt = e / 192;
    int rem = e - tt*192;
    const int rho = rem >> 5; rem &= 31;
    const int c = rem >> 3;
    const int el = rem & 7;
    const int row = 6*(tt>>3) + rho;
    const int col = ((tt&7)<<5) + (c<<3) + el;
    ((h2*)(ws + WS_REGW))[d] = PK(gwh[row*256+col], gwh[row*256+col+1]);
  }
}

// ------------------------------------------------------------------- K2
__global__ __attribute__((amdgpu_flat_work_group_size(1024,1024)))
void a3c_scan(
    const float* __restrict__ gbh,
    const float* __restrict__ aw,  const float* __restrict__ ab,
    const float* __restrict__ lnw, const float* __restrict__ lnb,
    float* __restrict__ ws)
{
  const int t = threadIdx.x;
  const int o = t >> 3, i = t & 7;

  __shared__ __align__(16) __fp16 h16[256];
  __shared__ float h32[256];
  __shared__ float pp[768*9];          // partials [row][9] (pad vs conflicts)
  __shared__ float bhl[768];
  __shared__ float gil[2][768];
  __shared__ __align__(16) float f0[128];

  if (t < 768){ bhl[t] = gbh[t]; gil[0][t] = ws[WS_GI + t]; }
  if (t < 256){ h16[t] = (__fp16)0.f; h32[t] = 0.f; }

  // 24 pinned fragments: rows 6o+rho, cols 32i+8c.. (+8); frag = rho*4+c
  const f4* rw = (const f4*)(ws + WS_REGW) + t*24;
  f4 W00=rw[0],  W01=rw[1],  W02=rw[2],  W03=rw[3];
  f4 W10=rw[4],  W11=rw[5],  W12=rw[6],  W13=rw[7];
  f4 W20=rw[8],  W21=rw[9],  W22=rw[10], W23=rw[11];
  f4 W30=rw[12], W31=rw[13], W32=rw[14], W33=rw[15];
  f4 W40=rw[16], W41=rw[17], W42=rw[18], W43=rw[19];
  f4 W50=rw[20], W51=rw[21], W52=rw[22], W53=rw[23];
  #define PIN(v) asm volatile("" : "+v"(v))
  PIN(W00);PIN(W01);PIN(W02);PIN(W03);PIN(W10);PIN(W11);PIN(W12);PIN(W13);
  PIN(W20);PIN(W21);PIN(W22);PIN(W23);PIN(W30);PIN(W31);PIN(W32);PIN(W33);
  PIN(W40);PIN(W41);PIN(W42);PIN(W43);PIN(W50);PIN(W51);PIN(W52);PIN(W53);
  #undef PIN
  __syncthreads();

  const int pbase = o*6;
  int cur = 0;
  for (int s=0; s<64; ++s){
    float gnx = 0.f;
    if (t < 768) gnx = ws[WS_GI + ((s<63)?(s+1):s)*768 + t];

    float a0=0.f,a1=0.f,a2=0.f,a3=0.f,a4=0.f,a5=0.f;
    #define CHUNK(c) { \
      const h8 hv = *(const h8*)(h16 + (i<<5) + ((c)<<3)); h8 w; \
      w=__builtin_bit_cast(h8,W0##c); \
      a0=FD(P0(w),P0(hv),a0); a0=FD(P1(w),P1(hv),a0); \
      a0=FD(P2(w),P2(hv),a0); a0=FD(P3(w),P3(hv),a0); \
      w=__builtin_bit_cast(h8,W1##c); \
      a1=FD(P0(w),P0(hv),a1); a1=FD(P1(w),P1(hv),a1); \
      a1=FD(P2(w),P2(hv),a1); a1=FD(P3(w),P3(hv),a1); \
      w=__builtin_bit_cast(h8,W2##c); \
      a2=FD(P0(w),P0(hv),a2); a2=FD(P1(w),P1(hv),a2); \
      a2=FD(P2(w),P2(hv),a2); a2=FD(P3(w),P3(hv),a2); \
      w=__builtin_bit_cast(h8,W3##c); \
      a3=FD(P0(w),P0(hv),a3); a3=FD(P1(w),P1(hv),a3); \
      a3=FD(P2(w),P2(hv),a3); a3=FD(P3(w),P3(hv),a3); \
      w=__builtin_bit_cast(h8,W4##c); \
      a4=FD(P0(w),P0(hv),a4); a4=FD(P1(w),P1(hv),a4); \
      a4=FD(P2(w),P2(hv),a4); a4=FD(P3(w),P3(hv),a4); \
      w=__builtin_bit_cast(h8,W5##c); \
      a5=FD(P0(w),P0(hv),a5); a5=FD(P1(w),P1(hv),a5); \
      a5=FD(P2(w),P2(hv),a5); a5=FD(P3(w),P3(hv),a5); }
    CHUNK(0) CHUNK(1) CHUNK(2) CHUNK(3)
    #undef CHUNK

    pp[(pbase+0)*9+i]=a0; pp[(pbase+1)*9+i]=a1; pp[(pbase+2)*9+i]=a2;
    pp[(pbase+3)*9+i]=a3; pp[(pbase+4)*9+i]=a4; pp[(pbase+5)*9+i]=a5;
    if (t < 768) gil[cur^1][t] = gnx;
    __syncthreads();
    if (t < 256){
      const float* pr = pp + t*9;
      const float* pz = pp + (256+t)*9;
      const float* pn = pp + (512+t)*9;
      float sr=bhl[t], sz=bhl[256+t], sn=bhl[512+t];
      #pragma unroll
      for (int k=0;k<8;++k){ sr+=pr[k]; sz+=pz[k]; sn+=pn[k]; }
      const float rr = sigm(gil[cur][t]       + sr);
      const float zz = sigm(gil[cur][256 + t] + sz);
      const float nn = tanhf(gil[cur][512 + t] + rr*sn);
      const float hv = (1.f - zz)*nn + zz*h32[t];
      h32[t] = hv;
      h16[t] = (__fp16)hv;
    }
    cur ^= 1;
    __syncthreads();
  }

  // ---- attention -> fuse -> lin (h_enc == h32)
  if (t < 128){
    const float4* wr = (const float4*)(aw + t*256);
    const float4* h4 = (const float4*)h32;
    float acc = ab[t];
    #pragma unroll 8
    for (int k=0;k<64;++k) acc += dot4(wr[k], h4[k]);
    f0[t] = ws[WS_IMG + t] * sigm(acc);
  }
  __syncthreads();
  if (t < 256){
    const float4* wr = (const float4*)(lnw + t*128);
    const float4* h4 = (const float4*)f0;
    float acc = lnb[t];
    #pragma unroll 8
    for (int k=0;k<32;++k) acc += dot4(wr[k], h4[k]);
    ws[WS_FUSED + t] = fmaxf(acc, 0.f);
  }
}

// ------------------------------------------------------------------- K3
__global__ __launch_bounds__(256) void a3c_post(
    const float* __restrict__ lwi, const float* __restrict__ lbi,
    const float* __restrict__ cx,
    const float* __restrict__ cw,  const float* __restrict__ acw,
    float* __restrict__ ws, float* __restrict__ out)
{
  const int p = blockIdx.x;            // 0..3, owns 64 LSTM units
  const int t = threadIdx.x;
  __shared__ __align__(16) float fused_lds[256];
  __shared__ float gv[256];
  __shared__ float hh[64];
  fused_lds[t] = ws[WS_FUSED + t];
  __syncthreads();
  const int g = t>>6, ul = t&63;
  const int R = (g<<8) + p*64 + ul;
  const float4* wr = (const float4*)(lwi + R*256);
  const float4* f4p = (const float4*)fused_lds;
  float acc = ws[WS_GATESH + R] + lbi[R];
  #pragma unroll 8
  for (int k=0;k<64;++k) acc += dot4(wr[k], f4p[k]);
  gv[t] = acc;
  __syncthreads();
  if (t < 64){
    const int u2 = p*64 + t;
    const float iv = gv[t], fv = gv[64+t], gg = gv[128+t], ov = gv[192+t];
    const float c = sigm(fv)*cx[u2] + sigm(iv)*tanhf(gg);
    const float h = sigm(ov)*tanhf(c);
    out[5   + u2] = h;
    out[261 + u2] = c;
    hh[t] = h;
  }
  __syncthreads();
  if (t < 64){
    #pragma unroll
    for (int o=0;o<5;++o){
      const float* wrow = (o==0) ? cw : (acw + (o-1)*288);
      float pr = hh[t]*wrow[p*64 + t];
      #pragma unroll
      for (int off=32; off; off>>=1) pr += __shfl_down(pr, off, 64);
      if (t == 0) atomicAdd(out + o, pr);
    }
  }
}

extern "C" void kernel_launch(void* const* d_in, const int* in_sizes, int n_in,
                              void* d_out, int out_size, void* d_ws, size_t ws_size,
                              hipStream_t stream) {
  (void)in_sizes; (void)n_in; (void)out_size; (void)ws_size;
  const float* x    = (const float*)d_in[0];
  const int*   inst = (const int*)  d_in[1];
  const int*   tx   = (const int*)  d_in[2];
  const float* hx   = (const float*)d_in[3];
  const float* cx   = (const float*)d_in[4];
  const float* i1w  = (const float*)d_in[5];
  const float* i1b  = (const float*)d_in[6];
  const float* i2w  = (const float*)d_in[7];
  const float* i2b  = (const float*)d_in[8];
  const float* i3w  = (const float*)d_in[9];
  const float* i3b  = (const float*)d_in[10];
  const float* emb  = (const float*)d_in[11];
  const float* gwi  = (const float*)d_in[12];
  const float* gwh  = (const float*)d_in[13];
  const float* gbi  = (const float*)d_in[14];
  const float* gbh  = (const float*)d_in[15];
  const float* aw   = (const float*)d_in[16];
  const float* ab   = (const float*)d_in[17];
  const float* temb = (const float*)d_in[18];
  const float* lnw  = (const float*)d_in[19];
  const float* lnb  = (const float*)d_in[20];
  const float* lwi  = (const float*)d_in[21];
  const float* lwh  = (const float*)d_in[22];
  const float* lbi  = (const float*)d_in[23];
  const float* lbh  = (const float*)d_in[24];
  const float* cw   = (const float*)d_in[25];
  const float* cb   = (const float*)d_in[26];
  const float* acw  = (const float*)d_in[27];
  const float* acb  = (const float*)d_in[28];
  float* ws  = (float*)d_ws;
  float* out = (float*)d_out;

  a3c_pre <<<582, 256, 0, stream>>>(x, i1w, i1b, i2w, i2b, i3w, i3b,
                                    hx, lwh, lbh, tx, temb, cw, cb, acw, acb,
                                    inst, emb, gwi, gbi, gwh, ws, out);
  a3c_scan<<<1, 1024, 0, stream>>>(gbh, aw, ab, lnw, lnb, ws);
  a3c_post<<<4, 256, 0, stream>>>(lwi, lbi, cx, cw, acw, ws, out);
}